// Round 9
// baseline (261.730 us; speedup 1.0000x reference)
//
#include <hip/hip_runtime.h>
#include <stdint.h>

// VanillaRNN fused: B=2048,S=125,I=2,H=300,O=2
// h_t = relu(x_t@W_ih^T + b_ih + h_{t-1}@W_hh^T + b_hh) + 0.01*noise_t
// out = h_t @ W_out^T + b_out
//
// 256 WGs x 320 threads (5 waves); each WG owns 8 batch rows for all 125
// steps. R9 structure change (R5-R8 post-mortem: LDS instruction pipe is
// the ~3800cy/step limiter -- 10 waves x 10 redundant ds_read_b128 A-frag
// reads = ~1200cy/step; wave count is the only lever since 10 reads/wave
// = K-tiles is irreducible):
//   - 5 waves x 64 cols (lane owns c0..c0+3, c0 = n0+4*lc) -> 50 A-reads.
//     wf = 4x10 frags = 160 regs; fits the 256-reg budget at 2 waves/EU
//     now that noise stages through LDS (R3/R4's failure was noise-in-reg
//     + 2x unroll pushing demand to ~290).
//   - noise via global_load_lds DMA, double-buffered, 1 step ahead;
//     epilogue reads it as ONE float4 per row.
//   - zero-row Abuf (9 rows): A-frag lanes lc>=8 broadcast a zero row
//     (R8's conflict halving, kept) -- but NO operand pre-hoist (R8's
//     regression: hoisted arrays spilled, WRITE_SIZE 41MB).
// W_out rides as pad COLUMNS 300/301 (wave 4, lane 11) -> no output reduce.

#define SEQ   125
#define HID   300
#define APAD  328     // Abuf row stride in shorts; 656B rows, 16B-aligned
#define KT    10
#define WAVES 5
#define NTH   (WAVES * 64)
#define RPW   8       // batch rows per WG
#define NCHUNKS (RPW * HID / 4)   // 600 16B DMA chunks per step

typedef __attribute__((ext_vector_type(8))) short bf16x8;
typedef __attribute__((ext_vector_type(4))) float f32x4;

__device__ __forceinline__ short f2bf(float f) {
  union { float f; uint32_t u; } v; v.f = f;
  uint32_t r = (v.u + 0x7fffu + ((v.u >> 16) & 1u)) >> 16;  // RNE
  return (short)r;
}

__device__ __forceinline__ uint32_t cvt_pk_bf16(float lo, float hi) {
  uint32_t r;
  asm("v_cvt_pk_bf16_f32 %0, %1, %2" : "=v"(r) : "v"(lo), "v"(hi));
  return r;
}

// async global->LDS 16B DMA: per-lane global src, wave-uniform LDS base
// (HW writes base + lane*16).
__device__ __forceinline__ void dma16(const float* g, float* l) {
  __builtin_amdgcn_global_load_lds(
      (const __attribute__((address_space(1))) unsigned int*)g,
      (__attribute__((address_space(3))) unsigned int*)l, 16, 0, 0);
}

__global__ __launch_bounds__(NTH, 1)
__attribute__((amdgpu_waves_per_eu(1, 2)))
void rnn_fused(
    const float* __restrict__ x,      // [2048,125,2]
    const float* __restrict__ noise,  // [2048,125,300]
    const float* __restrict__ W_ih,   // [300,2]
    const float* __restrict__ b_ih,   // [300]
    const float* __restrict__ W_hh,   // [300,300]
    const float* __restrict__ b_hh,   // [300]
    const float* __restrict__ W_out,  // [2,300]
    const float* __restrict__ b_out,  // [2]
    float* __restrict__ out)          // [2048,125,2]
{
  // rows 0..7 = h for the WG's 8 batch rows; row 8 = permanent zeros
  // (A-frag rows 8..15 of the 16x16 MFMA read it via broadcast).
  __shared__ __align__(16) short Abuf[2][9][APAD];    // 11808 B
  __shared__ __align__(16) float Nbuf[2][RPW * HID];  // 19200 B: noise, dbuf
  __shared__ float xbuf[RPW][SEQ * 2];                //  8000 B
  __shared__ float outbuf[RPW][SEQ * 2];              //  8000 B

  const int tid  = threadIdx.x;
  const int wave = tid >> 6;
  const int lane = tid & 63;
  const int grp  = lane >> 4;     // 0..3
  const int lc   = lane & 15;     // 0..15
  const int row0 = blockIdx.x * RPW;
  const int n0   = wave << 6;     // wave's 64-col base
  const int c0   = n0 + 4 * lc;   // lane's 4 cols: c0..c0+3
  const bool v0  = (c0 < HID);    // c0 mult of 4 => c0<300 means c0<=296, all 4 cols valid
  const bool rowv = (grp < 2);    // rows grp*4+r valid (RPW=8)
  const int arow = (lc < 8) ? lc : 8;   // zero-row broadcast for lc>=8

  // zero both h buffers incl. the shared zero row (never written again)
  for (int i = tid; i < 2 * 9 * APAD / 2; i += NTH)
    ((uint32_t*)Abuf)[i] = 0u;
  // stage x
  for (int i = tid; i < RPW * SEQ * 2; i += NTH) {
    int r = i / (SEQ * 2), j = i % (SEQ * 2);
    xbuf[r][j] = x[(row0 + r) * (SEQ * 2) + j];
  }

  // per-lane column constants (zeroed for pad cols)
  float wih0[4], wih1[4], biasc[4];
#pragma unroll
  for (int j = 0; j < 4; ++j) {
    int c = c0 + j;
    bool v = (c < HID);
    int cc = v ? c : 0;
    wih0[j]  = v ? W_ih[cc * 2 + 0] : 0.f;
    wih1[j]  = v ? W_ih[cc * 2 + 1] : 0.f;
    biasc[j] = v ? (b_ih[cc] + b_hh[cc]) : 0.f;
  }
  const float bout0 = b_out[0], bout1 = b_out[1];

  // persistent B fragments: lane supplies col c0+j at MFMA n=lc for tile j.
  // cols 300/301 carry W_out rows 0/1 (fused output projection).
  bf16x8 wf[4][KT];
#pragma unroll
  for (int j = 0; j < 4; ++j) {
    int c = c0 + j;
#pragma unroll
    for (int kt = 0; kt < KT; ++kt) {
      bf16x8 f;
#pragma unroll
      for (int e = 0; e < 8; ++e) {
        int k = kt * 32 + grp * 8 + e;
        float v = 0.f;
        if (k < HID) {
          if (c < HID)            v = W_hh[c * HID + k];
          else if (c == HID)      v = W_out[k];
          else if (c == HID + 1)  v = W_out[HID + k];
        }
        f[e] = f2bf(v);
      }
      wf[j][kt] = f;
    }
  }

  // ---- noise DMA: 600 chunks, 320 threads -> 2 rounds ----
  // round 0: chunk = tid (all lanes); round 1: chunk = tid + 320 (masked)
  const int ch1 = tid + NTH;
  const bool dma1 = (ch1 < NCHUNKS);
  const float* gsrc0 = noise + (size_t)(row0 + tid / 75) * (SEQ * HID) + (tid % 75) * 4;
  const float* gsrc1 = noise + (size_t)(row0 + ch1 / 75) * (SEQ * HID) + (ch1 % 75) * 4;

  // pre-stage noise for step 0 into Nbuf[0]
  dma16(gsrc0, &Nbuf[0][wave * 256]);
  if (dma1) dma16(gsrc1, &Nbuf[0][NTH * 4 + wave * 256]);
  gsrc0 += HID; gsrc1 += HID;  // -> step 1

  __syncthreads();  // drains vmcnt(0): Nbuf[0] ready; Abuf/xbuf visible

  // Iteration s (0..125): MFMA on h_{s-1}; extract out[s-1] (s>=1);
  // epilogue builds h_s (s<125). 126 iterations.
  for (int s = 0; s <= SEQ; ++s) {
    const int cur = s & 1, nxt = cur ^ 1;

    // DMA-prefetch noise for step s+1 into Nbuf[nxt] (lands by this step's
    // closing __syncthreads vmcnt(0) drain; readers of Nbuf[nxt] finished
    // before the PREVIOUS barrier -> no WAR race).
    if (s + 1 < SEQ) {
      dma16(gsrc0, &Nbuf[nxt][wave * 256]);
      if (dma1) dma16(gsrc1, &Nbuf[nxt][NTH * 4 + wave * 256]);
    }
    gsrc0 += HID; gsrc1 += HID;

    // ---- MFMA: K=320, 4 n-tiles (cols c0..c0+3 per lane) ----
    const short* Ab = &Abuf[cur][arow][grp * 8];
    f32x4 ac0 = {0.f,0.f,0.f,0.f}, ac1 = {0.f,0.f,0.f,0.f};
    f32x4 ac2 = {0.f,0.f,0.f,0.f}, ac3 = {0.f,0.f,0.f,0.f};
#pragma unroll
    for (int kt = 0; kt < KT; ++kt) {
      bf16x8 a = *(const bf16x8*)(Ab + kt * 32);
      ac0 = __builtin_amdgcn_mfma_f32_16x16x32_bf16(a, wf[0][kt], ac0, 0,0,0);
      ac1 = __builtin_amdgcn_mfma_f32_16x16x32_bf16(a, wf[1][kt], ac1, 0,0,0);
      ac2 = __builtin_amdgcn_mfma_f32_16x16x32_bf16(a, wf[2][kt], ac2, 0,0,0);
      ac3 = __builtin_amdgcn_mfma_f32_16x16x32_bf16(a, wf[3][kt], ac3, 0,0,0);
    }

    // fused output projection (cols 300/301 = tiles j=0/1 of wave4/lc11)
    if (s >= 1 && wave == 4 && lc == 11 && rowv) {
#pragma unroll
      for (int r = 0; r < 4; ++r) {
        outbuf[grp * 4 + r][(s - 1) * 2 + 0] = ac0[r] + bout0;
        outbuf[grp * 4 + r][(s - 1) * 2 + 1] = ac1[r] + bout1;
      }
    }

    if (s < SEQ) {
      if (rowv) {
#pragma unroll
        for (int r = 0; r < 4; ++r) {
          int lrow = grp * 4 + r;
          float2 xv = *(const float2*)&xbuf[lrow][s * 2];
          float h0 = fmaxf(ac0[r] + xv.x * wih0[0] + xv.y * wih1[0] + biasc[0], 0.f);
          float h1 = fmaxf(ac1[r] + xv.x * wih0[1] + xv.y * wih1[1] + biasc[1], 0.f);
          float h2 = fmaxf(ac2[r] + xv.x * wih0[2] + xv.y * wih1[2] + biasc[2], 0.f);
          float h3 = fmaxf(ac3[r] + xv.x * wih0[3] + xv.y * wih1[3] + biasc[3], 0.f);
          if (v0) {  // c0<=296 => all 4 cols valid
            float4 nz = *(const float4*)&Nbuf[cur][lrow * HID + c0];
            h0 += 0.01f * nz.x;
            h1 += 0.01f * nz.y;
            h2 += 0.01f * nz.z;
            h3 += 0.01f * nz.w;
          }
          uint2 pk;
          pk.x = cvt_pk_bf16(h0, h1);
          pk.y = cvt_pk_bf16(h2, h3);
          *(uint2*)&Abuf[nxt][lrow][c0] = pk;
        }
      }
      __syncthreads();
    }
  }

  __syncthreads();  // outbuf visible to all

  // coalesced flush of staged outputs
  for (int i = tid; i < RPW * SEQ * 2; i += NTH) {
    int r = i / (SEQ * 2), j = i % (SEQ * 2);
    out[(row0 + r) * (SEQ * 2) + j] = outbuf[r][j];
  }
}

extern "C" void kernel_launch(void* const* d_in, const int* in_sizes, int n_in,
                              void* d_out, int out_size, void* d_ws, size_t ws_size,
                              hipStream_t stream) {
  const float* xp     = (const float*)d_in[0];
  const float* noise  = (const float*)d_in[1];
  const float* W_ih   = (const float*)d_in[2];
  const float* b_ih   = (const float*)d_in[3];
  const float* W_hh   = (const float*)d_in[4];
  const float* b_hh   = (const float*)d_in[5];
  const float* W_out  = (const float*)d_in[6];
  const float* b_out  = (const float*)d_in[7];
  float* outp         = (float*)d_out;

  rnn_fused<<<dim3(2048 / RPW), dim3(NTH), 0, stream>>>(
      xp, noise, W_ih, b_ih, W_hh, b_hh, W_out, b_out, outp);
}

// Round 10
// 200.003 us; speedup vs baseline: 1.3086x; 1.3086x over previous
//
#include <hip/hip_runtime.h>
#include <stdint.h>

// VanillaRNN fused: B=2048,S=125,I=2,H=300,O=2
// h_t = relu(x_t@W_ih^T + b_ih + h_{t-1}@W_hh^T + b_hh) + 0.01*noise_t
// out = h_t @ W_out^T + b_out
//
// R10 = R7's shape (the only near-spill-free config: 10 waves x 32 cols,
// wf=80 regs, WRITE_SIZE 11.6MB) + pipelined noise DMA:
//   - noise prefetched TWO steps ahead into a TRIPLE-buffered LDS stage
//     via global_load_lds; each wave issues exactly 1 DMA per step.
//   - step barrier = single asm volatile "s_waitcnt vmcnt(1) lgkmcnt(0);
//     s_barrier" (memory clobber): the older in-flight DMA (needed next
//     step) is complete, the newer stays in flight ACROSS the barrier --
//     removes the ~900-1500cy/step HBM drain that __syncthreads'
//     vmcnt(0) imposed in R5-R9. vmcnt retires in order; single-asm
//     emission closes R4's hoisting-window race.
//   - zero-row Abuf: A-frag lanes lc>=8 broadcast a shared zero row
//     (halves A-read traffic + kills the 2-way b128 conflict).
// W_out rides as pad COLUMNS 300/301 (wave 9, lane 6) -> no output reduce.

#define SEQ   125
#define HID   300
#define APAD  328     // Abuf row stride in shorts; 656B rows, 16B-aligned
#define KT    10
#define WAVES 10
#define NTH   (WAVES * 64)
#define RPW   8       // batch rows per WG
#define NCHUNKS (RPW * HID / 4)   // 600 16B DMA chunks per step

typedef __attribute__((ext_vector_type(8))) short bf16x8;
typedef __attribute__((ext_vector_type(4))) float f32x4;

__device__ __forceinline__ short f2bf(float f) {
  union { float f; uint32_t u; } v; v.f = f;
  uint32_t r = (v.u + 0x7fffu + ((v.u >> 16) & 1u)) >> 16;  // RNE
  return (short)r;
}

__device__ __forceinline__ uint32_t cvt_pk_bf16(float lo, float hi) {
  uint32_t r;
  asm("v_cvt_pk_bf16_f32 %0, %1, %2" : "=v"(r) : "v"(lo), "v"(hi));
  return r;
}

// async global->LDS 16B DMA: per-lane global src, wave-uniform LDS base
// (HW writes base + lane*16; exec-masked lanes skipped).
__device__ __forceinline__ void dma16(const float* g, float* l) {
  __builtin_amdgcn_global_load_lds(
      (const __attribute__((address_space(1))) unsigned int*)g,
      (__attribute__((address_space(3))) unsigned int*)l, 16, 0, 0);
}

// Counted-vmcnt step barrier. ONE asm block: nothing can be scheduled
// between the waitcnt and s_barrier; "memory" stops LDS/VMEM ops crossing.
// vmcnt(1): the OLDER of the two in-flight noise DMAs has retired (its
// LDS write is visible after the barrier); the newer stays in flight.
#define STEP_BARRIER() \
  asm volatile("s_waitcnt vmcnt(1) lgkmcnt(0)\n\ts_barrier" ::: "memory")

__global__ __launch_bounds__(NTH)
__attribute__((amdgpu_waves_per_eu(3, 3)))
void rnn_fused(
    const float* __restrict__ x,      // [2048,125,2]
    const float* __restrict__ noise,  // [2048,125,300]
    const float* __restrict__ W_ih,   // [300,2]
    const float* __restrict__ b_ih,   // [300]
    const float* __restrict__ W_hh,   // [300,300]
    const float* __restrict__ b_hh,   // [300]
    const float* __restrict__ W_out,  // [2,300]
    const float* __restrict__ b_out,  // [2]
    float* __restrict__ out)          // [2048,125,2]
{
  // rows 0..7 = h for the WG's 8 batch rows; row 8 = permanent zeros.
  __shared__ __align__(16) short Abuf[2][9][APAD];      // 11808 B
  __shared__ __align__(16) float Nbuf[3][NCHUNKS * 4];  // 28800 B: noise, 3-buf
  __shared__ float xbuf[RPW][SEQ * 2];                  //  8000 B
  __shared__ float outbuf[RPW][SEQ * 2];                //  8000 B

  const int tid  = threadIdx.x;
  const int wave = tid >> 6;
  const int lane = tid & 63;
  const int grp  = lane >> 4;     // 0..3
  const int lc   = lane & 15;     // 0..15
  const int row0 = blockIdx.x * RPW;
  const int n0   = wave << 5;     // wave's 32-col base
  const int c0   = n0 + 2 * lc;   // even col
  const int c1   = c0 + 1;        // odd col
  const bool v0  = (c0 < HID), v1 = (c1 < HID);
  const bool rowv = (grp < 2);    // rows grp*4+r valid (RPW=8)
  const int arow = (lc < 8) ? lc : 8;   // zero-row broadcast for lc>=8

  // zero both h buffers incl. the shared zero row (never written again)
  for (int i = tid; i < 2 * 9 * APAD / 2; i += NTH)
    ((uint32_t*)Abuf)[i] = 0u;
  // stage x
  for (int i = tid; i < RPW * SEQ * 2; i += NTH) {
    int r = i / (SEQ * 2), j = i % (SEQ * 2);
    xbuf[r][j] = x[(row0 + r) * (SEQ * 2) + j];
  }

  // per-lane column constants (zeroed for pad cols)
  const float wih00 = v0 ? W_ih[c0 * 2 + 0] : 0.f;
  const float wih10 = v0 ? W_ih[c0 * 2 + 1] : 0.f;
  const float wih01 = v1 ? W_ih[c1 * 2 + 0] : 0.f;
  const float wih11 = v1 ? W_ih[c1 * 2 + 1] : 0.f;
  const float biasc0 = v0 ? (b_ih[c0] + b_hh[c0]) : 0.f;
  const float biasc1 = v1 ? (b_ih[c1] + b_hh[c1]) : 0.f;
  const float bout0 = b_out[0], bout1 = b_out[1];

  // persistent B fragments: lane supplies cols c0 (wf0) / c1 (wf1) at MFMA n=lc.
  // cols 300/301 carry W_out rows 0/1 (fused output projection).
  bf16x8 wf0[KT], wf1[KT];
#pragma unroll
  for (int kt = 0; kt < KT; ++kt) {
    bf16x8 f0, f1;
#pragma unroll
    for (int e = 0; e < 8; ++e) {
      int k = kt * 32 + grp * 8 + e;
      float a = 0.f, b = 0.f;
      if (k < HID) {
        if (c0 < HID)           a = W_hh[c0 * HID + k];
        else if (c0 == HID)     a = W_out[k];
        if (c1 < HID)           b = W_hh[c1 * HID + k];
        else if (c1 == HID)     b = W_out[k];
        else if (c1 == HID + 1) b = W_out[HID + k];
      }
      f0[e] = f2bf(a);
      f1[e] = f2bf(b);
    }
    wf0[kt] = f0; wf1[kt] = f1;
  }

  // ---- noise DMA: chunk = tid (600 chunks; waves 0..8 full, wave 9
  // 24 active lanes -> every wave issues exactly 1 DMA instr per step).
  // chunk c covers floats [4c..4c+4) of the [8][300] step-slab; LDS dest
  // wave*256 + lane*4 == 4*tid == 4c (exact match, contiguous).
  const bool dma = (tid < NCHUNKS);
  const float* gsrc = dma
      ? noise + (size_t)(row0 + tid / 75) * (SEQ * HID) + (tid % 75) * 4
      : noise;  // unused

  __syncthreads();  // full drain: init loads retired (vmcnt->0), LDS visible

  // prologue: DMAs for steps 0 and 1
  if (dma) {
    dma16(gsrc, &Nbuf[0][wave * 256]);
    dma16(gsrc + HID, &Nbuf[1][wave * 256]);
  }
  const float* gsrc2 = gsrc + 2 * HID;  // next issue position (step 2)
  STEP_BARRIER();  // vmcnt(1): step-0 noise landed; step-1 in flight

  int rb = 0;  // s % 3 (read buffer)
  for (int s = 0; s <= SEQ; ++s) {
    const int cur = s & 1, nxt = cur ^ 1;
    int wb = rb + 2; if (wb >= 3) wb -= 3;  // (s+2) % 3 (DMA target)

    // DMA-prefetch noise for step s+2 (2 full steps to cover HBM latency;
    // clamped re-load of the last slab near the tail keeps vmcnt uniform)
    if (dma && s < SEQ) dma16(gsrc2, &Nbuf[wb][wave * 256]);
    if (s + 3 < SEQ) gsrc2 += HID;

    // ---- MFMA: K=320, 2 n-tiles (cols c0/c1), 4 chains of 5 ----
    const short* Ab = &Abuf[cur][arow][grp * 8];
    f32x4 a0a = {0.f,0.f,0.f,0.f}, a0b = {0.f,0.f,0.f,0.f};
    f32x4 a1a = {0.f,0.f,0.f,0.f}, a1b = {0.f,0.f,0.f,0.f};
#pragma unroll
    for (int kt = 0; kt < KT; kt += 2) {
      bf16x8 aa = *(const bf16x8*)(Ab + kt * 32);
      bf16x8 ab = *(const bf16x8*)(Ab + (kt + 1) * 32);
      a0a = __builtin_amdgcn_mfma_f32_16x16x32_bf16(aa, wf0[kt],     a0a, 0,0,0);
      a1a = __builtin_amdgcn_mfma_f32_16x16x32_bf16(aa, wf1[kt],     a1a, 0,0,0);
      a0b = __builtin_amdgcn_mfma_f32_16x16x32_bf16(ab, wf0[kt + 1], a0b, 0,0,0);
      a1b = __builtin_amdgcn_mfma_f32_16x16x32_bf16(ab, wf1[kt + 1], a1b, 0,0,0);
    }
    f32x4 ac0 = a0a + a0b, ac1 = a1a + a1b;

    // fused output projection (cols 300/301): out[s-1]
    if (s >= 1 && wave == 9 && lc == 6 && rowv) {
#pragma unroll
      for (int r = 0; r < 4; ++r) {
        outbuf[grp * 4 + r][(s - 1) * 2 + 0] = ac0[r] + bout0;
        outbuf[grp * 4 + r][(s - 1) * 2 + 1] = ac1[r] + bout1;
      }
    }

    if (s < SEQ) {
      if (rowv) {
#pragma unroll
        for (int r = 0; r < 4; ++r) {
          int lrow = grp * 4 + r;
          float2 xv = *(const float2*)&xbuf[lrow][s * 2];
          float h0 = fmaxf(ac0[r] + xv.x * wih00 + xv.y * wih10 + biasc0, 0.f);
          float h1 = fmaxf(ac1[r] + xv.x * wih01 + xv.y * wih11 + biasc1, 0.f);
          if (v0) {  // c0 even <300 => c1 also valid
            float2 nz = *(const float2*)&Nbuf[rb][lrow * HID + c0];
            h0 += 0.01f * nz.x;
            h1 += 0.01f * nz.y;
          }
          *(uint32_t*)&Abuf[nxt][lrow][c0] = cvt_pk_bf16(h0, h1);
        }
      }
      STEP_BARRIER();
    }
    ++rb; if (rb == 3) rb = 0;
  }

  __syncthreads();  // full drain; outbuf visible to all

  // coalesced flush of staged outputs
  for (int i = tid; i < RPW * SEQ * 2; i += NTH) {
    int r = i / (SEQ * 2), j = i % (SEQ * 2);
    out[(row0 + r) * (SEQ * 2) + j] = outbuf[r][j];
  }
}

extern "C" void kernel_launch(void* const* d_in, const int* in_sizes, int n_in,
                              void* d_out, int out_size, void* d_ws, size_t ws_size,
                              hipStream_t stream) {
  const float* xp     = (const float*)d_in[0];
  const float* noise  = (const float*)d_in[1];
  const float* W_ih   = (const float*)d_in[2];
  const float* b_ih   = (const float*)d_in[3];
  const float* W_hh   = (const float*)d_in[4];
  const float* b_hh   = (const float*)d_in[5];
  const float* W_out  = (const float*)d_in[6];
  const float* b_out  = (const float*)d_in[7];
  float* outp         = (float*)d_out;

  rnn_fused<<<dim3(2048 / RPW), dim3(NTH), 0, stream>>>(
      xp, noise, W_ih, b_ih, W_hh, b_hh, W_out, b_out, outp);
}

// Round 11
// 141.328 us; speedup vs baseline: 1.8519x; 1.4152x over previous
//
#include <hip/hip_runtime.h>
#include <stdint.h>

// VanillaRNN fused: B=2048,S=125,I=2,H=300,O=2
// h_t = relu(x_t@W_ih^T + b_ih + h_{t-1}@W_hh^T + b_hh) + 0.01*noise_t
// out = h_t @ W_out^T + b_out
//
// R11: SWAPPED MFMA (A=W in registers, B=h from LDS) + x/bias K-fold.
//  - A/B frag lane-mappings are identical (idx=l&15, k=(l>>4)*8+e), so
//    swapping operand order keeps the SAME h LDS read pattern but
//    transposes C: lane owns 1 batch row (lc) x 4 CONTIGUOUS cols
//    (grp*4+r) per tile -> epilogue = 2x ds_read_b128 (noise float4) +
//    2x ds_write_b64 (h) per wave vs 8 ops before.
//  - K-rows 300/301/302 of the h tile carry x0,x1,1.0; wf rows 300-302
//    carry W_ih cols / (b_ih+b_hh) -> xbuf reads + 4 FMA*2 + bias adds
//    deleted from the epilogue. 8 lanes write next step's x cols (1 op).
//  - W_out = wf COLS 300/301 (wave 9 t0 grp3); b_out added fp32 at the
//    out-write. Out rows k=300..302 of W_out cols are 0 (out has no x).
//  - 6-unrolled step loop: cur/rb/wb compile-time -> all LDS addresses
//    are base-VGPR + immediate offset (zero addressing VALU in loop).
//  - Kept from R7-R10: 10 waves x 32 cols (wf=80 regs, the only
//    non-spilling shape), zero-row broadcast Abuf, triple-buffered noise
//    DMA 2 steps ahead with single-asm vmcnt(1) barrier.

#define SEQ   125
#define HID   300
#define APAD  328     // Abuf row stride in shorts; 656B rows, 16B-aligned
#define KT    10
#define WAVES 10
#define NTH   (WAVES * 64)
#define RPW   8
#define NCH   600     // 16B DMA chunks per step-slab (8*300*4B/16)
#define NSLAB 2408    // floats per Nbuf slab (2400 + 8 pad)

typedef __attribute__((ext_vector_type(8))) short bf16x8;
typedef __attribute__((ext_vector_type(4))) float f32x4;

__device__ __forceinline__ short f2bf(float f) {
  union { float f; uint32_t u; } v; v.f = f;
  uint32_t r = (v.u + 0x7fffu + ((v.u >> 16) & 1u)) >> 16;  // RNE
  return (short)r;
}

__device__ __forceinline__ uint32_t cvt_pk_bf16(float lo, float hi) {
  uint32_t r;
  asm("v_cvt_pk_bf16_f32 %0, %1, %2" : "=v"(r) : "v"(lo), "v"(hi));
  return r;
}

__device__ __forceinline__ void dma16(const float* g, float* l) {
  __builtin_amdgcn_global_load_lds(
      (const __attribute__((address_space(1))) unsigned int*)g,
      (__attribute__((address_space(3))) unsigned int*)l, 16, 0, 0);
}

// Single-asm counted barrier: vmcnt(1) -> older of the 2 in-flight noise
// DMAs has landed; newer stays in flight across the barrier. lgkmcnt(0)
// -> own ds reads/writes done. One asm block = no hoisting window.
#define STEP_BARRIER() \
  asm volatile("s_waitcnt vmcnt(1) lgkmcnt(0)\n\ts_barrier" ::: "memory")

__global__ __launch_bounds__(NTH)
__attribute__((amdgpu_waves_per_eu(3, 3)))
void rnn_fused(
    const float* __restrict__ x,      // [2048,125,2]
    const float* __restrict__ noise,  // [2048,125,300]
    const float* __restrict__ W_ih,   // [300,2]
    const float* __restrict__ b_ih,   // [300]
    const float* __restrict__ W_hh,   // [300,300]
    const float* __restrict__ b_hh,   // [300]
    const float* __restrict__ W_out,  // [2,300]
    const float* __restrict__ b_out,  // [2]
    float* __restrict__ out)          // [2048,125,2]
{
  // rows 0..7 = batch rows' h (+x cols 300-301, bias col 302); row 8 = zeros
  __shared__ __align__(16) short Abuf[2][9][APAD];   // 11808 B
  __shared__ __align__(16) float Nbuf[3][NSLAB];     // 28896 B noise 3-buf
  __shared__ float xbuf[RPW][SEQ * 2];               //  8000 B
  __shared__ float outbuf[RPW][SEQ * 2];             //  8000 B

  const int tid  = threadIdx.x;
  const int wave = tid >> 6;
  const int lane = tid & 63;
  const int grp  = lane >> 4;     // 0..3
  const int lc   = lane & 15;     // 0..15
  const int row0 = blockIdx.x * RPW;
  const int grp8 = grp * 8;
  const int arow = (lc < 8) ? lc : 8;     // zero-row broadcast
  const bool lcr = (lc < 8);              // lane's batch row is real
  const bool w9  = (wave == 9);
  const int cb0  = wave * 32 + grp * 4;   // tile0 output-col base (D rows)
  const int nb0  = lc * HID + cb0;        // noise float index (tile0)

  // zero both Abuf buffers (incl. zero-row + cols 302..327)
  for (int i = tid; i < 2 * 9 * APAD / 2; i += NTH)
    ((uint32_t*)Abuf)[i] = 0u;
  // stage x
  for (int i = tid; i < RPW * SEQ * 2; i += NTH) {
    int r = i / (SEQ * 2), j = i % (SEQ * 2);
    xbuf[r][j] = x[(row0 + r) * (SEQ * 2) + j];
  }

  const float bout0 = b_out[0], bout1 = b_out[1];

  // ---- persistent A-side fragments: wf[t][kt], lane holds W for col
  // c = wave*32 + t*16 + lc, k = kt*32 + grp*8 + e.
  // k=300/301: W_ih cols; k=302: b_ih+b_hh; c=300/301: W_out rows (k<300).
  bf16x8 wf0[KT], wf1[KT];
#pragma unroll
  for (int t = 0; t < 2; ++t) {
    int c = wave * 32 + t * 16 + lc;
#pragma unroll
    for (int kt = 0; kt < KT; ++kt) {
      bf16x8 f;
#pragma unroll
      for (int e = 0; e < 8; ++e) {
        int k = kt * 32 + grp8 + e;
        float v = 0.f;
        if (c < HID) {
          if (k < HID)            v = W_hh[c * HID + k];
          else if (k == HID)      v = W_ih[c * 2 + 0];
          else if (k == HID + 1)  v = W_ih[c * 2 + 1];
          else if (k == HID + 2)  v = b_ih[c] + b_hh[c];
        } else if (c == HID) {         // out col 0: pure W_out row 0
          if (k < HID)            v = W_out[k];
        } else if (c == HID + 1) {     // out col 1
          if (k < HID)            v = W_out[HID + k];
        }
        f[e] = f2bf(v);
      }
      if (t == 0) wf0[kt] = f; else wf1[kt] = f;
    }
  }

  // ---- noise DMA: chunk = tid; dest = slab + tid*16B (wave-linear) ----
  const bool dma = (tid < NCH);
  const float* gsrc = dma
      ? noise + (size_t)(row0 + tid / 75) * (SEQ * HID) + (tid % 75) * 4
      : noise;

  __syncthreads();  // Abuf zeros + xbuf visible

  // post-zero init: x_0 into Abuf[0] cols 300-301; bias-one col 302 (both)
  if (tid < 8) {
    float2 xv = *(const float2*)&x[(size_t)(row0 + tid) * (SEQ * 2)];
    *(uint32_t*)&Abuf[0][tid][300] = cvt_pk_bf16(xv.x, xv.y);
    Abuf[0][tid][302] = (short)0x3F80;   // bf16 1.0
    Abuf[1][tid][302] = (short)0x3F80;
  }

  // prologue DMA: slabs 0 and 1
  if (dma) {
    dma16(gsrc, &Nbuf[0][wave * 256]);
    dma16(gsrc + HID, &Nbuf[1][wave * 256]);
  }
  const float* gsrc2 = gsrc + 2 * HID;
  STEP_BARRIER();  // slab 0 landed; slab 1 in flight; init LDS visible

  const bool xw = (wave == 0) && (grp == 0) && lcr;  // lanes 0-7

  // Iteration S: MFMA on Abuf[CUR] (= h_{S-1} + x_S + bias); out[S-1]
  // extracted from cols 300/301 (S>=1); epilogue writes h_S + x_{S+1}
  // into Abuf[CUR^1] (S<SEQ).
#define STEPM(S, CUR, RB, WB, DO_OUT, DO_EPI, DO_X, DO_ADV, DO_DMA)            \
  {                                                                            \
    if (DO_DMA) { if (dma) dma16(gsrc2, &Nbuf[WB][wave * 256]); }              \
    if (DO_ADV) gsrc2 += HID;                                                  \
    const short* Ab = &Abuf[CUR][arow][grp8];                                  \
    f32x4 t0a = {0.f,0.f,0.f,0.f}, t0b = {0.f,0.f,0.f,0.f};                    \
    f32x4 t1a = {0.f,0.f,0.f,0.f}, t1b = {0.f,0.f,0.f,0.f};                    \
    _Pragma("unroll")                                                          \
    for (int kt = 0; kt < KT; kt += 2) {                                       \
      bf16x8 ha = *(const bf16x8*)(Ab + kt * 32);                              \
      bf16x8 hb = *(const bf16x8*)(Ab + kt * 32 + 32);                         \
      t0a = __builtin_amdgcn_mfma_f32_16x16x32_bf16(wf0[kt],     ha, t0a, 0,0,0); \
      t1a = __builtin_amdgcn_mfma_f32_16x16x32_bf16(wf1[kt],     ha, t1a, 0,0,0); \
      t0b = __builtin_amdgcn_mfma_f32_16x16x32_bf16(wf0[kt + 1], hb, t0b, 0,0,0); \
      t1b = __builtin_amdgcn_mfma_f32_16x16x32_bf16(wf1[kt + 1], hb, t1b, 0,0,0); \
    }                                                                          \
    f32x4 ac0 = t0a + t0b, ac1 = t1a + t1b;                                    \
    if (w9) {                                                                  \
      if (DO_OUT) { if (grp == 3 && lcr) {                                     \
        float2 o; o.x = ac0[0] + bout0; o.y = ac0[1] + bout1;                  \
        *(float2*)&outbuf[lc][((S) - 1) * 2] = o;                              \
      } }                                                                      \
      if (DO_EPI) { if (lcr && grp < 3) {                                      \
        float4 nz = *(const float4*)&Nbuf[RB][nb0];                            \
        float h0 = fmaxf(ac0[0], 0.f) + 0.01f * nz.x;                          \
        float h1 = fmaxf(ac0[1], 0.f) + 0.01f * nz.y;                          \
        float h2 = fmaxf(ac0[2], 0.f) + 0.01f * nz.z;                          \
        float h3 = fmaxf(ac0[3], 0.f) + 0.01f * nz.w;                          \
        uint2 pk; pk.x = cvt_pk_bf16(h0, h1); pk.y = cvt_pk_bf16(h2, h3);      \
        *(uint2*)&Abuf[(CUR) ^ 1][lc][cb0] = pk;                               \
      } }                                                                      \
    } else {                                                                   \
      if (DO_EPI) { if (lcr) {                                                 \
        float4 nz0 = *(const float4*)&Nbuf[RB][nb0];                           \
        float4 nz1 = *(const float4*)&Nbuf[RB][nb0 + 16];                      \
        float a0 = fmaxf(ac0[0], 0.f) + 0.01f * nz0.x;                         \
        float a1 = fmaxf(ac0[1], 0.f) + 0.01f * nz0.y;                         \
        float a2 = fmaxf(ac0[2], 0.f) + 0.01f * nz0.z;                         \
        float a3 = fmaxf(ac0[3], 0.f) + 0.01f * nz0.w;                         \
        float b0 = fmaxf(ac1[0], 0.f) + 0.01f * nz1.x;                         \
        float b1 = fmaxf(ac1[1], 0.f) + 0.01f * nz1.y;                         \
        float b2 = fmaxf(ac1[2], 0.f) + 0.01f * nz1.z;                         \
        float b3 = fmaxf(ac1[3], 0.f) + 0.01f * nz1.w;                         \
        uint2 p0; p0.x = cvt_pk_bf16(a0, a1); p0.y = cvt_pk_bf16(a2, a3);      \
        uint2 p1; p1.x = cvt_pk_bf16(b0, b1); p1.y = cvt_pk_bf16(b2, b3);      \
        *(uint2*)&Abuf[(CUR) ^ 1][lc][cb0] = p0;                               \
        *(uint2*)&Abuf[(CUR) ^ 1][lc][cb0 + 16] = p1;                          \
      } }                                                                      \
    }                                                                          \
    if (DO_X) { if (xw) {                                                      \
      float2 xv = *(const float2*)&xbuf[lc][((S) + 1) * 2];                    \
      *(uint32_t*)&Abuf[(CUR) ^ 1][lc][300] = cvt_pk_bf16(xv.x, xv.y);         \
    } }                                                                        \
    if (DO_EPI) STEP_BARRIER();                                                \
  }

  // peeled first block (S=0..5): no out-write at S=0
  STEPM(0, 0, 0, 2, 0, 1, 1, 1, 1);
  STEPM(1, 1, 1, 0, 1, 1, 1, 1, 1);
  STEPM(2, 0, 2, 1, 1, 1, 1, 1, 1);
  STEPM(3, 1, 0, 2, 1, 1, 1, 1, 1);
  STEPM(4, 0, 1, 0, 1, 1, 1, 1, 1);
  STEPM(5, 1, 2, 1, 1, 1, 1, 1, 1);

  // main: S = 6..119 (19 blocks of 6; all guards statically true)
  for (int s = 6; s < 120; s += 6) {
    STEPM(s + 0, 0, 0, 2, 1, 1, 1, 1, 1);
    STEPM(s + 1, 1, 1, 0, 1, 1, 1, 1, 1);
    STEPM(s + 2, 0, 2, 1, 1, 1, 1, 1, 1);
    STEPM(s + 3, 1, 0, 2, 1, 1, 1, 1, 1);
    STEPM(s + 4, 0, 1, 0, 1, 1, 1, 1, 1);
    STEPM(s + 5, 1, 2, 1, 1, 1, 1, 1, 1);
  }

  // tail S=120..125 (static guards; slab-124 re-issues keep vmcnt uniform)
  STEPM(120, 0, 0, 2, 1, 1, 1, 1, 1);
  STEPM(121, 1, 1, 0, 1, 1, 1, 1, 1);
  STEPM(122, 0, 2, 1, 1, 1, 1, 0, 1);  // no more advance (slab 124 is last)
  STEPM(123, 1, 0, 2, 1, 1, 1, 0, 1);
  STEPM(124, 0, 1, 0, 1, 1, 0, 0, 1);  // no x_125
  STEPM(125, 1, 2, 1, 1, 0, 0, 0, 0);  // MFMA + out[124] only, no barrier

#undef STEPM

  __syncthreads();  // full drain; outbuf visible

  // coalesced flush
  for (int i = tid; i < RPW * SEQ * 2; i += NTH) {
    int r = i / (SEQ * 2), j = i % (SEQ * 2);
    out[(row0 + r) * (SEQ * 2) + j] = outbuf[r][j];
  }
}

extern "C" void kernel_launch(void* const* d_in, const int* in_sizes, int n_in,
                              void* d_out, int out_size, void* d_ws, size_t ws_size,
                              hipStream_t stream) {
  const float* xp     = (const float*)d_in[0];
  const float* noise  = (const float*)d_in[1];
  const float* W_ih   = (const float*)d_in[2];
  const float* b_ih   = (const float*)d_in[3];
  const float* W_hh   = (const float*)d_in[4];
  const float* b_hh   = (const float*)d_in[5];
  const float* W_out  = (const float*)d_in[6];
  const float* b_out  = (const float*)d_in[7];
  float* outp         = (float*)d_out;

  rnn_fused<<<dim3(2048 / RPW), dim3(NTH), 0, stream>>>(
      xp, noise, W_ih, b_ih, W_hh, b_hh, W_out, b_out, outp);
}